// Round 1
// baseline (3983.921 us; speedup 1.0000x reference)
//
#include <hip/hip_runtime.h>

#define TILE 64
#define BK   16
#define PAD  4   // keeps 16B alignment for ds_*_b128, breaks 4-way store conflicts to 2-way (free)

// ---------------- helpers ----------------
__global__ __launch_bounds__(256) void zero_f32(float* __restrict__ p, int n) {
    int i = blockIdx.x * 256 + threadIdx.x;
    if (i < n) p[i] = 0.0f;
}

__global__ __launch_bounds__(256) void degree_accum(const int* __restrict__ dst,
                                                    float* __restrict__ deg, int E) {
    int e = blockIdx.x * 256 + threadIdx.x;
    if (e < E) atomicAdd(&deg[dst[e]], 1.0f);
}

__global__ __launch_bounds__(256) void make_dinv(float* __restrict__ deg, int n) {
    int i = blockIdx.x * 256 + threadIdx.x;
    if (i < n) deg[i] = rsqrtf(deg[i] + 1.0f);
}

// ---------------- fp32 tiled GEMM: C[M,N](ldc) = A[M,K](lda) @ B[K,N](ldb=N) + bias0 + bias1
__global__ __launch_bounds__(256) void gemm_bias(
    const float* __restrict__ A, int lda,
    const float* __restrict__ B,
    const float* __restrict__ bias0,
    const float* __restrict__ bias1,
    float* __restrict__ C, int ldc,
    int M, int N, int K)
{
    __shared__ float As[BK][TILE + PAD]; // As[k][m]
    __shared__ float Bs[BK][TILE + PAD]; // Bs[k][n]

    const int bm = blockIdx.x * TILE;
    const int bn = blockIdx.y * TILE;
    const int tid = threadIdx.x;          // 0..255
    const int tx = tid & 15;              // n-direction (4 cols each)
    const int ty = tid >> 4;              // m-direction (4 rows each)

    float acc[4][4] = {};

    const int a_row = tid >> 2;           // 0..63
    const int a_kq  = (tid & 3) << 2;     // 0,4,8,12
    const int b_kr  = tid >> 4;           // 0..15
    const int b_nq  = (tid & 15) << 2;    // 0..60

    for (int k0 = 0; k0 < K; k0 += BK) {
        // stage A tile (64 rows x 16 k), coalesced float4 along k
        {
            int gm = bm + a_row;
            float4 v = make_float4(0.f, 0.f, 0.f, 0.f);
            if (gm < M) v = *(const float4*)&A[(size_t)gm * lda + k0 + a_kq];
            As[a_kq + 0][a_row] = v.x;
            As[a_kq + 1][a_row] = v.y;
            As[a_kq + 2][a_row] = v.z;
            As[a_kq + 3][a_row] = v.w;
        }
        // stage B tile (16 k x 64 n), coalesced float4 along n
        {
            int gn = bn + b_nq;
            float4 v = make_float4(0.f, 0.f, 0.f, 0.f);
            if (gn + 3 < N)  // N is a multiple of 4 in all our calls
                v = *(const float4*)&B[(size_t)(k0 + b_kr) * N + gn];
            *(float4*)&Bs[b_kr][b_nq] = v;
        }
        __syncthreads();

        #pragma unroll
        for (int k = 0; k < BK; ++k) {
            float4 a = *(const float4*)&As[k][ty << 2];
            float4 b = *(const float4*)&Bs[k][tx << 2];
            float av[4] = {a.x, a.y, a.z, a.w};
            float bv[4] = {b.x, b.y, b.z, b.w};
            #pragma unroll
            for (int i = 0; i < 4; ++i)
                #pragma unroll
                for (int j = 0; j < 4; ++j)
                    acc[i][j] = fmaf(av[i], bv[j], acc[i][j]);
        }
        __syncthreads();
    }

    #pragma unroll
    for (int i = 0; i < 4; ++i) {
        int gm = bm + (ty << 2) + i;
        if (gm >= M) continue;
        #pragma unroll
        for (int j = 0; j < 4; ++j) {
            int gn = bn + (tx << 2) + j;
            if (gn >= N) continue;
            float v = acc[i][j];
            if (bias0) v += bias0[gn];
            if (bias1) v += bias1[gn];
            C[(size_t)gm * ldc + gn] = v;
        }
    }
}

// ---------------- edge scatter: agg[dst,f] += hw[src,f] * dinv[src]*dinv[dst]
// one block per edge, 256 threads = 256 features
__global__ __launch_bounds__(256) void scatter_edges(
    const int* __restrict__ src, const int* __restrict__ dst,
    const float* __restrict__ dinv,
    const float* __restrict__ hw,
    float* __restrict__ agg, int E)
{
    int e = blockIdx.x;
    int f = threadIdx.x;
    int s = src[e];
    int d = dst[e];
    float norm = dinv[s] * dinv[d];
    float v = hw[(size_t)s * 256 + f] * norm;
    atomicAdd(&agg[(size_t)d * 256 + f], v);
}

// ---------------- finalize: h' = relu(agg + hw*dinv^2) -> jk column block
__global__ __launch_bounds__(256) void finalize_layer(
    const float* __restrict__ agg,
    const float* __restrict__ hw,
    const float* __restrict__ dinv,
    float* __restrict__ jk_col,   // jk + layer*256, row stride 1024
    int n)
{
    int i = blockIdx.x;
    int f = threadIdx.x;
    float sn = dinv[i] * dinv[i];
    float v = agg[(size_t)i * 256 + f] + hw[(size_t)i * 256 + f] * sn;
    v = fmaxf(v, 0.0f);
    jk_col[(size_t)i * 1024 + f] = v;
}

extern "C" void kernel_launch(void* const* d_in, const int* in_sizes, int n_in,
                              void* d_out, int out_size, void* d_ws, size_t ws_size,
                              hipStream_t stream) {
    const float* x        = (const float*)d_in[0];
    const int*   ei       = (const int*)d_in[1];
    const float* in_gc_W  = (const float*)d_in[2];
    const float* in_gc_b  = (const float*)d_in[3];
    const float* in_lin_W = (const float*)d_in[4];
    const float* in_lin_b = (const float*)d_in[5];
    const float* convs_W  = (const float*)d_in[6];
    const float* convs_b  = (const float*)d_in[7];
    const float* lins_W   = (const float*)d_in[8];
    const float* lins_b   = (const float*)d_in[9];
    const float* out_W    = (const float*)d_in[10];
    const float* out_b    = (const float*)d_in[11];

    const int N = 50000;
    const int E = in_sizes[1] / 2;
    const int F = 512, H = 256, L = 4, NC = 40;

    const int* src = ei;
    const int* dst = ei + E;

    // workspace carve-up
    char* ws = (char*)d_ws;
    float* dinv = (float*)ws;  ws += (((size_t)N * 4) + 255) & ~(size_t)255;
    float* hw   = (float*)ws;  ws += (size_t)N * H * 4;
    float* agg  = (float*)ws;  ws += (size_t)N * H * 4;
    float* jk   = (float*)ws;  ws += (size_t)N * H * L * 4;
    float* out  = (float*)d_out;

    // 1) degrees -> dinv
    zero_f32<<<(N + 255) / 256, 256, 0, stream>>>(dinv, N);
    degree_accum<<<(E + 255) / 256, 256, 0, stream>>>(dst, dinv, E);
    make_dinv<<<(N + 255) / 256, 256, 0, stream>>>(dinv, N);

    const dim3 gemm_grid((N + TILE - 1) / TILE, H / TILE);   // 782 x 4
    const dim3 out_grid((N + TILE - 1) / TILE, 1);           // N=40 fits one 64-tile

    // 2) layers
    for (int l = 0; l < L; ++l) {
        const float* Aprev = (l == 0) ? x : (jk + (size_t)(l - 1) * H);
        int lda            = (l == 0) ? F : H * L;
        int K              = (l == 0) ? F : H;
        const float* gcW   = (l == 0) ? in_gc_W  : (convs_W + (size_t)(l - 1) * H * H);
        const float* gcB   = (l == 0) ? in_gc_b  : (convs_b + (size_t)(l - 1) * H);
        const float* liW   = (l == 0) ? in_lin_W : (lins_W  + (size_t)(l - 1) * H * H);
        const float* liB   = (l == 0) ? in_lin_b : (lins_b  + (size_t)(l - 1) * H);

        // agg <- A@lin_W + lin_b + gc_b   (also serves as agg init; no zeroing needed)
        gemm_bias<<<gemm_grid, 256, 0, stream>>>(Aprev, lda, liW, liB, gcB, agg, H, N, H, K);
        // hw <- A@gc_W
        gemm_bias<<<gemm_grid, 256, 0, stream>>>(Aprev, lda, gcW, nullptr, nullptr, hw, H, N, H, K);
        // scatter edges
        scatter_edges<<<E, 256, 0, stream>>>(src, dst, dinv, hw, agg, E);
        // finalize into jk column block l
        finalize_layer<<<N, 256, 0, stream>>>(agg, hw, dinv, jk + (size_t)l * H, N);
    }

    // 3) output GEMM: out = jk @ out_W + out_b
    gemm_bias<<<out_grid, 256, 0, stream>>>(jk, H * L, out_W, out_b, nullptr,
                                            out, NC, N, NC, H * L);
}

// Round 2
// 1796.370 us; speedup vs baseline: 2.2178x; 2.2178x over previous
//
#include <hip/hip_runtime.h>

#define TILE 64
#define BK   16
#define PAD  4

// ---------------- small helpers ----------------
__global__ __launch_bounds__(256) void zero_i32(int* __restrict__ p, int n) {
    int i = blockIdx.x * 256 + threadIdx.x;
    if (i < n) p[i] = 0;
}

__global__ __launch_bounds__(256) void hist_dst(const int* __restrict__ dst,
                                                int* __restrict__ count, int E) {
    int e = blockIdx.x * 256 + threadIdx.x;
    if (e < E) atomicAdd(&count[dst[e]], 1);
}

__global__ __launch_bounds__(256) void make_dinv(const int* __restrict__ count,
                                                 float* __restrict__ dinv, int n) {
    int i = blockIdx.x * 256 + threadIdx.x;
    if (i < n) dinv[i] = rsqrtf(1.0f + (float)count[i]);
}

// ---------------- 3-step exclusive scan over count[N] -> rowptr[N] ----------------
__global__ __launch_bounds__(256) void scan_block(const int* __restrict__ count,
                                                  int* __restrict__ incl,
                                                  int* __restrict__ blocksum, int n) {
    __shared__ int tmp[256];
    int t = threadIdx.x;
    int i = blockIdx.x * 256 + t;
    int v = (i < n) ? count[i] : 0;
    tmp[t] = v;
    __syncthreads();
    for (int off = 1; off < 256; off <<= 1) {
        int x = (t >= off) ? tmp[t - off] : 0;
        __syncthreads();
        tmp[t] += x;
        __syncthreads();
    }
    if (i < n) incl[i] = tmp[t];
    if (t == 255) blocksum[blockIdx.x] = tmp[255];
}

__global__ __launch_bounds__(256) void scan_top(const int* __restrict__ blocksum,
                                                int* __restrict__ blockoff, int nb) {
    __shared__ int tmp[256];
    int t = threadIdx.x;
    int v = (t < nb) ? blocksum[t] : 0;
    tmp[t] = v;
    __syncthreads();
    for (int off = 1; off < 256; off <<= 1) {
        int x = (t >= off) ? tmp[t - off] : 0;
        __syncthreads();
        tmp[t] += x;
        __syncthreads();
    }
    if (t < nb) blockoff[t] = tmp[t] - v;  // exclusive
}

__global__ __launch_bounds__(256) void make_rowptr(const int* __restrict__ incl,
                                                   const int* __restrict__ count,
                                                   const int* __restrict__ blockoff,
                                                   int* __restrict__ rowptr,
                                                   int* __restrict__ cursor, int n) {
    int i = blockIdx.x * 256 + threadIdx.x;
    if (i < n) {
        int r = incl[i] - count[i] + blockoff[blockIdx.x];
        rowptr[i] = r;
        cursor[i] = r;
    }
}

__global__ __launch_bounds__(256) void scatter_perm(const int* __restrict__ src,
                                                    const int* __restrict__ dst,
                                                    const float* __restrict__ dinv,
                                                    int* __restrict__ cursor,
                                                    int* __restrict__ sorted_src,
                                                    float* __restrict__ sorted_norm, int E) {
    int e = blockIdx.x * 256 + threadIdx.x;
    if (e < E) {
        int d = dst[e], s = src[e];
        int slot = atomicAdd(&cursor[d], 1);
        sorted_src[slot] = s;
        sorted_norm[slot] = dinv[s] * dinv[d];
    }
}

// ---------------- fp32 tiled GEMM: C[M,N](ldc) = A[M,K](lda) @ B[K,N](ldb=N) + bias0 + bias1
__global__ __launch_bounds__(256) void gemm_bias(
    const float* __restrict__ A, int lda,
    const float* __restrict__ B,
    const float* __restrict__ bias0,
    const float* __restrict__ bias1,
    float* __restrict__ C, int ldc,
    int M, int N, int K)
{
    __shared__ float As[BK][TILE + PAD];
    __shared__ float Bs[BK][TILE + PAD];

    const int bm = blockIdx.x * TILE;
    const int bn = blockIdx.y * TILE;
    const int tid = threadIdx.x;
    const int tx = tid & 15;
    const int ty = tid >> 4;

    float acc[4][4] = {};

    const int a_row = tid >> 2;
    const int a_kq  = (tid & 3) << 2;
    const int b_kr  = tid >> 4;
    const int b_nq  = (tid & 15) << 2;

    for (int k0 = 0; k0 < K; k0 += BK) {
        {
            int gm = bm + a_row;
            float4 v = make_float4(0.f, 0.f, 0.f, 0.f);
            if (gm < M) v = *(const float4*)&A[(size_t)gm * lda + k0 + a_kq];
            As[a_kq + 0][a_row] = v.x;
            As[a_kq + 1][a_row] = v.y;
            As[a_kq + 2][a_row] = v.z;
            As[a_kq + 3][a_row] = v.w;
        }
        {
            int gn = bn + b_nq;
            float4 v = make_float4(0.f, 0.f, 0.f, 0.f);
            if (gn + 3 < N)
                v = *(const float4*)&B[(size_t)(k0 + b_kr) * N + gn];
            *(float4*)&Bs[b_kr][b_nq] = v;
        }
        __syncthreads();

        #pragma unroll
        for (int k = 0; k < BK; ++k) {
            float4 a = *(const float4*)&As[k][ty << 2];
            float4 b = *(const float4*)&Bs[k][tx << 2];
            float av[4] = {a.x, a.y, a.z, a.w};
            float bv[4] = {b.x, b.y, b.z, b.w};
            #pragma unroll
            for (int i = 0; i < 4; ++i)
                #pragma unroll
                for (int j = 0; j < 4; ++j)
                    acc[i][j] = fmaf(av[i], bv[j], acc[i][j]);
        }
        __syncthreads();
    }

    #pragma unroll
    for (int i = 0; i < 4; ++i) {
        int gm = bm + (ty << 2) + i;
        if (gm >= M) continue;
        #pragma unroll
        for (int j = 0; j < 4; ++j) {
            int gn = bn + (tx << 2) + j;
            if (gn >= N) continue;
            float v = acc[i][j];
            if (bias0) v += bias0[gn];
            if (bias1) v += bias1[gn];
            C[(size_t)gm * ldc + gn] = v;
        }
    }
}

// ---------------- fused CSR aggregate + self-loop + relu, in-place on jk column
// one wave (64 lanes) per dst node; lane covers 4 features (float4).
// jk_col points at jk + layer*256; row stride 1024. It already holds
// lin_out + lin_b + gc_b (from the GEMM). We add sum_{e in} hw[src]*norm
// + hw[i]*dinv[i]^2, relu, write back.
__global__ __launch_bounds__(256) void aggregate_csr(
    const int* __restrict__ rowptr, const int* __restrict__ count,
    const int* __restrict__ sorted_src, const float* __restrict__ sorted_norm,
    const float* __restrict__ dinv,
    const float* __restrict__ hw,
    float* __restrict__ jk_col, int n)
{
    int wave = (blockIdx.x * 256 + threadIdx.x) >> 6;
    int lane = threadIdx.x & 63;
    if (wave >= n) return;
    const int i = wave;

    const int start = rowptr[i];
    const int deg   = count[i];

    float* jrow = &jk_col[(size_t)i * 1024 + lane * 4];
    float4 acc = *(const float4*)jrow;

    for (int base = 0; base < deg; base += 64) {
        int m = deg - base;
        if (m > 64) m = 64;
        int   s_l  = 0;
        float nm_l = 0.0f;
        if (lane < m) {
            s_l  = sorted_src[start + base + lane];
            nm_l = sorted_norm[start + base + lane];
        }
        for (int j = 0; j < m; ++j) {
            int   s  = __shfl(s_l, j, 64);
            float nm = __shfl(nm_l, j, 64);
            float4 h = *(const float4*)&hw[(size_t)s * 256 + lane * 4];
            acc.x = fmaf(h.x, nm, acc.x);
            acc.y = fmaf(h.y, nm, acc.y);
            acc.z = fmaf(h.z, nm, acc.z);
            acc.w = fmaf(h.w, nm, acc.w);
        }
    }

    float di = dinv[i];
    float sn = di * di;
    float4 hs = *(const float4*)&hw[(size_t)i * 256 + lane * 4];
    acc.x = fmaxf(fmaf(hs.x, sn, acc.x), 0.0f);
    acc.y = fmaxf(fmaf(hs.y, sn, acc.y), 0.0f);
    acc.z = fmaxf(fmaf(hs.z, sn, acc.z), 0.0f);
    acc.w = fmaxf(fmaf(hs.w, sn, acc.w), 0.0f);
    *(float4*)jrow = acc;
}

extern "C" void kernel_launch(void* const* d_in, const int* in_sizes, int n_in,
                              void* d_out, int out_size, void* d_ws, size_t ws_size,
                              hipStream_t stream) {
    const float* x        = (const float*)d_in[0];
    const int*   ei       = (const int*)d_in[1];
    const float* in_gc_W  = (const float*)d_in[2];
    const float* in_gc_b  = (const float*)d_in[3];
    const float* in_lin_W = (const float*)d_in[4];
    const float* in_lin_b = (const float*)d_in[5];
    const float* convs_W  = (const float*)d_in[6];
    const float* convs_b  = (const float*)d_in[7];
    const float* lins_W   = (const float*)d_in[8];
    const float* lins_b   = (const float*)d_in[9];
    const float* out_W    = (const float*)d_in[10];
    const float* out_b    = (const float*)d_in[11];

    const int N = 50000;
    const int E = in_sizes[1] / 2;
    const int F = 512, H = 256, L = 4, NC = 40;

    const int* src = ei;
    const int* dst = ei + E;

    // workspace carve-up (all 256B-aligned)
    char* ws = (char*)d_ws;
    auto carve = [&](size_t bytes) { void* p = ws; ws += (bytes + 255) & ~(size_t)255; return p; };
    float* dinv       = (float*)carve((size_t)N * 4);
    int*   count      = (int*)  carve((size_t)N * 4);
    int*   incl       = (int*)  carve((size_t)N * 4);
    int*   rowptr     = (int*)  carve((size_t)N * 4);
    int*   cursor     = (int*)  carve((size_t)N * 4);
    int*   blocksum   = (int*)  carve(256 * 4);
    int*   blockoff   = (int*)  carve(256 * 4);
    int*   sorted_src = (int*)  carve((size_t)E * 4);
    float* sorted_nrm = (float*)carve((size_t)E * 4);
    float* hw         = (float*)carve((size_t)N * H * 4);
    float* jk         = (float*)carve((size_t)N * H * L * 4);
    float* out        = (float*)d_out;

    const int nbN = (N + 255) / 256;     // 196
    const int nbE = (E + 255) / 256;     // 3125

    // 1) CSR build + dinv (once per call)
    zero_i32<<<nbN, 256, 0, stream>>>(count, N);
    hist_dst<<<nbE, 256, 0, stream>>>(dst, count, E);
    make_dinv<<<nbN, 256, 0, stream>>>(count, dinv, N);
    scan_block<<<nbN, 256, 0, stream>>>(count, incl, blocksum, N);
    scan_top<<<1, 256, 0, stream>>>(blocksum, blockoff, nbN);
    make_rowptr<<<nbN, 256, 0, stream>>>(incl, count, blockoff, rowptr, cursor, N);
    scatter_perm<<<nbE, 256, 0, stream>>>(src, dst, dinv, cursor, sorted_src, sorted_nrm, E);

    const dim3 gemm_grid((N + TILE - 1) / TILE, H / TILE);
    const dim3 out_grid((N + TILE - 1) / TILE, 1);
    const int agg_blocks = (N + 3) / 4;  // 4 waves/block, wave per node

    // 2) layers
    for (int l = 0; l < L; ++l) {
        const float* Aprev = (l == 0) ? x : (jk + (size_t)(l - 1) * H);
        int lda            = (l == 0) ? F : H * L;
        int K              = (l == 0) ? F : H;
        const float* gcW   = (l == 0) ? in_gc_W  : (convs_W + (size_t)(l - 1) * H * H);
        const float* gcB   = (l == 0) ? in_gc_b  : (convs_b + (size_t)(l - 1) * H);
        const float* liW   = (l == 0) ? in_lin_W : (lins_W  + (size_t)(l - 1) * H * H);
        const float* liB   = (l == 0) ? in_lin_b : (lins_b  + (size_t)(l - 1) * H);

        float* jk_col = jk + (size_t)l * H;

        // jk_col <- A@lin_W + lin_b + gc_b   (row stride 1024)
        gemm_bias<<<gemm_grid, 256, 0, stream>>>(Aprev, lda, liW, liB, gcB, jk_col, H * L, N, H, K);
        // hw <- A@gc_W
        gemm_bias<<<gemm_grid, 256, 0, stream>>>(Aprev, lda, gcW, nullptr, nullptr, hw, H, N, H, K);
        // fused CSR aggregate + self term + relu (in-place on jk_col)
        aggregate_csr<<<agg_blocks, 256, 0, stream>>>(rowptr, count, sorted_src, sorted_nrm,
                                                      dinv, hw, jk_col, N);
    }

    // 3) output GEMM: out = jk @ out_W + out_b
    gemm_bias<<<out_grid, 256, 0, stream>>>(jk, H * L, out_W, out_b, nullptr,
                                            out, NC, N, NC, H * L);
}

// Round 3
// 841.885 us; speedup vs baseline: 4.7321x; 2.1337x over previous
//
#include <hip/hip_runtime.h>

typedef _Float16 half8 __attribute__((ext_vector_type(8)));
typedef _Float16 half4 __attribute__((ext_vector_type(4)));
typedef float floatx4 __attribute__((ext_vector_type(4)));

// ---------------- small helpers ----------------
__global__ __launch_bounds__(256) void zero_i32(int* __restrict__ p, int n) {
    int i = blockIdx.x * 256 + threadIdx.x;
    if (i < n) p[i] = 0;
}

__global__ __launch_bounds__(256) void hist_dst(const int* __restrict__ dst,
                                                int* __restrict__ count, int E) {
    int e = blockIdx.x * 256 + threadIdx.x;
    if (e < E) atomicAdd(&count[dst[e]], 1);
}

__global__ __launch_bounds__(256) void make_dinv(const int* __restrict__ count,
                                                 float* __restrict__ dinv, int n) {
    int i = blockIdx.x * 256 + threadIdx.x;
    if (i < n) dinv[i] = rsqrtf(1.0f + (float)count[i]);
}

// cast fp32 -> fp16, 4 elems/thread
__global__ __launch_bounds__(256) void cast_f32_f16(const float* __restrict__ in,
                                                    _Float16* __restrict__ out, int n4) {
    int i = blockIdx.x * 256 + threadIdx.x;
    if (i < n4) {
        float4 v = *(const float4*)&in[(size_t)i * 4];
        half4 h = { (_Float16)v.x, (_Float16)v.y, (_Float16)v.z, (_Float16)v.w };
        *(half4*)&out[(size_t)i * 4] = h;
    }
}

// W[K x N] fp32 -> WT[N x K] fp16. grid.x = K, thread = n.
__global__ __launch_bounds__(256) void transpose_cast(const float* __restrict__ W,
                                                      _Float16* __restrict__ WT,
                                                      int K, int N) {
    int k = blockIdx.x;
    int n = threadIdx.x;
    if (n < N) WT[(size_t)n * K + k] = (_Float16)W[(size_t)k * N + n];
}

// ---------------- scan for CSR ----------------
__global__ __launch_bounds__(256) void scan_block(const int* __restrict__ count,
                                                  int* __restrict__ incl,
                                                  int* __restrict__ blocksum, int n) {
    __shared__ int tmp[256];
    int t = threadIdx.x;
    int i = blockIdx.x * 256 + t;
    int v = (i < n) ? count[i] : 0;
    tmp[t] = v;
    __syncthreads();
    for (int off = 1; off < 256; off <<= 1) {
        int x = (t >= off) ? tmp[t - off] : 0;
        __syncthreads();
        tmp[t] += x;
        __syncthreads();
    }
    if (i < n) incl[i] = tmp[t];
    if (t == 255) blocksum[blockIdx.x] = tmp[255];
}

__global__ __launch_bounds__(256) void scan_top(const int* __restrict__ blocksum,
                                                int* __restrict__ blockoff, int nb) {
    __shared__ int tmp[256];
    int t = threadIdx.x;
    int v = (t < nb) ? blocksum[t] : 0;
    tmp[t] = v;
    __syncthreads();
    for (int off = 1; off < 256; off <<= 1) {
        int x = (t >= off) ? tmp[t - off] : 0;
        __syncthreads();
        tmp[t] += x;
        __syncthreads();
    }
    if (t < nb) blockoff[t] = tmp[t] - v;  // exclusive
}

__global__ __launch_bounds__(256) void make_rowptr(const int* __restrict__ incl,
                                                   const int* __restrict__ count,
                                                   const int* __restrict__ blockoff,
                                                   int* __restrict__ rowptr,
                                                   int* __restrict__ cursor, int n) {
    int i = blockIdx.x * 256 + threadIdx.x;
    if (i < n) {
        int r = incl[i] - count[i] + blockoff[blockIdx.x];
        rowptr[i] = r;
        cursor[i] = r;
    }
}

__global__ __launch_bounds__(256) void scatter_perm(const int* __restrict__ src,
                                                    const int* __restrict__ dst,
                                                    const float* __restrict__ dinv,
                                                    int* __restrict__ cursor,
                                                    int* __restrict__ sorted_src,
                                                    float* __restrict__ sorted_norm, int E) {
    int e = blockIdx.x * 256 + threadIdx.x;
    if (e < E) {
        int d = dst[e], s = src[e];
        int slot = atomicAdd(&cursor[d], 1);
        sorted_src[slot] = s;
        sorted_norm[slot] = dinv[s] * dinv[d];
    }
}

// ---------------- fp16 MFMA GEMM ----------------
// C[M x N] = A[M x K](lda, fp16) @ BT[N x K]^T(fp16, row stride K) + bias0 + bias1
// Output: fp32 to Cf (if Ch==null) else fp16 to Ch. ldc in elements.
// BM=BN=128, BK=64. 256 threads = 4 waves in 2x2; wave does 4x4 frags of 16x16x32.
#define GBM 128
#define GBK 64
#define LSTR 72   // 64 + 8 halves pad: row stride 144B -> lanes r,r+8 alias (2-way, free)

__global__ __launch_bounds__(256) void gemm_f16(
    const _Float16* __restrict__ A, int lda,
    const _Float16* __restrict__ BT,
    const float* __restrict__ bias0,
    const float* __restrict__ bias1,
    float* __restrict__ Cf, _Float16* __restrict__ Ch, int ldc,
    int M, int N, int K)
{
    __shared__ _Float16 As[GBM * LSTR];
    __shared__ _Float16 Bs[GBM * LSTR];

    const int tid  = threadIdx.x;
    const int wave = tid >> 6;
    const int lane = tid & 63;
    const int q    = lane >> 4;   // quad 0..3
    const int r    = lane & 15;

    const int wm = (wave & 1) * 64;   // wave m-offset in tile
    const int wn = (wave >> 1) * 64;  // wave n-offset

    const int bm = blockIdx.x * GBM;
    const int bn = blockIdx.y * GBM;

    floatx4 acc[4][4] = {};

    for (int k0 = 0; k0 < K; k0 += GBK) {
        // stage A and B tiles: 128 rows x 64 halves each; 4 chunks of 16B per thread
        #pragma unroll
        for (int i = 0; i < 4; ++i) {
            int c = tid + i * 256;          // 0..1023
            int row = c >> 3;               // 0..127
            int koff = (c & 7) * 8;         // 0..56
            {
                int gm = bm + row; if (gm > M - 1) gm = M - 1;
                uint4 v = *(const uint4*)&A[(size_t)gm * lda + k0 + koff];
                *(uint4*)&As[row * LSTR + koff] = v;
            }
            {
                int gn = bn + row; if (gn > N - 1) gn = N - 1;
                uint4 v = *(const uint4*)&BT[(size_t)gn * K + k0 + koff];
                *(uint4*)&Bs[row * LSTR + koff] = v;
            }
        }
        __syncthreads();

        #pragma unroll
        for (int kk = 0; kk < 2; ++kk) {   // two 16x16x32 k-steps per 64-chunk
            half8 af[4], bf[4];
            #pragma unroll
            for (int mi = 0; mi < 4; ++mi)
                af[mi] = *(const half8*)&As[(wm + mi * 16 + r) * LSTR + kk * 32 + q * 8];
            #pragma unroll
            for (int ni = 0; ni < 4; ++ni)
                bf[ni] = *(const half8*)&Bs[(wn + ni * 16 + r) * LSTR + kk * 32 + q * 8];
            #pragma unroll
            for (int mi = 0; mi < 4; ++mi)
                #pragma unroll
                for (int ni = 0; ni < 4; ++ni)
                    acc[mi][ni] = __builtin_amdgcn_mfma_f32_16x16x32_f16(
                        af[mi], bf[ni], acc[mi][ni], 0, 0, 0);
        }
        __syncthreads();
    }

    // epilogue: C/D layout col = lane&15, row = q*4 + reg
    #pragma unroll
    for (int mi = 0; mi < 4; ++mi) {
        #pragma unroll
        for (int ni = 0; ni < 4; ++ni) {
            int col = bn + wn + ni * 16 + r;
            if (col >= N) continue;
            float badd = 0.0f;
            if (bias0) badd += bias0[col];
            if (bias1) badd += bias1[col];
            #pragma unroll
            for (int reg = 0; reg < 4; ++reg) {
                int gm = bm + wm + mi * 16 + q * 4 + reg;
                if (gm >= M) continue;
                float v = acc[mi][ni][reg] + badd;
                if (Ch) Ch[(size_t)gm * ldc + col] = (_Float16)v;
                else    Cf[(size_t)gm * ldc + col] = v;
            }
        }
    }
}

// ---------------- fused CSR aggregate + self-loop + relu -> jk_h (fp16)
// one wave per dst node; lane covers 4 features.
// h = lin[i] + sum_e hw[src]*norm + hw[i]*dinv^2; jk_h[i, l*256+f] = relu(h)
__global__ __launch_bounds__(256) void aggregate_csr(
    const int* __restrict__ rowptr, const int* __restrict__ count,
    const int* __restrict__ sorted_src, const float* __restrict__ sorted_norm,
    const float* __restrict__ dinv,
    const _Float16* __restrict__ hw,
    const float* __restrict__ lin,
    _Float16* __restrict__ jk_col,   // jk_h + l*256, row stride 1024
    int n)
{
    int wave = (blockIdx.x * 256 + threadIdx.x) >> 6;
    int lane = threadIdx.x & 63;
    if (wave >= n) return;
    const int i = wave;

    const int start = rowptr[i];
    const int deg   = count[i];

    float4 acc = *(const float4*)&lin[(size_t)i * 256 + lane * 4];

    for (int base = 0; base < deg; base += 64) {
        int m = deg - base;
        if (m > 64) m = 64;
        int   s_l  = 0;
        float nm_l = 0.0f;
        if (lane < m) {
            s_l  = sorted_src[start + base + lane];
            nm_l = sorted_norm[start + base + lane];
        }
        for (int j = 0; j < m; ++j) {
            int   s  = __shfl(s_l, j, 64);
            float nm = __shfl(nm_l, j, 64);
            half4 h = *(const half4*)&hw[(size_t)s * 256 + lane * 4];
            acc.x = fmaf((float)h[0], nm, acc.x);
            acc.y = fmaf((float)h[1], nm, acc.y);
            acc.z = fmaf((float)h[2], nm, acc.z);
            acc.w = fmaf((float)h[3], nm, acc.w);
        }
    }

    float di = dinv[i];
    float sn = di * di;
    half4 hs = *(const half4*)&hw[(size_t)i * 256 + lane * 4];
    acc.x = fmaxf(fmaf((float)hs[0], sn, acc.x), 0.0f);
    acc.y = fmaxf(fmaf((float)hs[1], sn, acc.y), 0.0f);
    acc.z = fmaxf(fmaf((float)hs[2], sn, acc.z), 0.0f);
    acc.w = fmaxf(fmaf((float)hs[3], sn, acc.w), 0.0f);

    half4 o = { (_Float16)acc.x, (_Float16)acc.y, (_Float16)acc.z, (_Float16)acc.w };
    *(half4*)&jk_col[(size_t)i * 1024 + lane * 4] = o;
}

extern "C" void kernel_launch(void* const* d_in, const int* in_sizes, int n_in,
                              void* d_out, int out_size, void* d_ws, size_t ws_size,
                              hipStream_t stream) {
    const float* x        = (const float*)d_in[0];
    const int*   ei       = (const int*)d_in[1];
    const float* in_gc_W  = (const float*)d_in[2];
    const float* in_gc_b  = (const float*)d_in[3];
    const float* in_lin_W = (const float*)d_in[4];
    const float* in_lin_b = (const float*)d_in[5];
    const float* convs_W  = (const float*)d_in[6];
    const float* convs_b  = (const float*)d_in[7];
    const float* lins_W   = (const float*)d_in[8];
    const float* lins_b   = (const float*)d_in[9];
    const float* out_W    = (const float*)d_in[10];
    const float* out_b    = (const float*)d_in[11];

    const int N = 50000;
    const int E = in_sizes[1] / 2;
    const int F = 512, H = 256, L = 4, NC = 40;

    const int* src = ei;
    const int* dst = ei + E;

    // workspace carve-up (256B aligned)
    char* ws = (char*)d_ws;
    auto carve = [&](size_t bytes) { void* p = ws; ws += (bytes + 255) & ~(size_t)255; return p; };
    float*    dinv       = (float*)carve((size_t)N * 4);
    int*      count      = (int*)  carve((size_t)N * 4);
    int*      incl       = (int*)  carve((size_t)N * 4);
    int*      rowptr     = (int*)  carve((size_t)N * 4);
    int*      cursor     = (int*)  carve((size_t)N * 4);
    int*      blocksum   = (int*)  carve(256 * 4);
    int*      blockoff   = (int*)  carve(256 * 4);
    int*      sorted_src = (int*)  carve((size_t)E * 4);
    float*    sorted_nrm = (float*)carve((size_t)E * 4);
    _Float16* xh         = (_Float16*)carve((size_t)N * F * 2);
    _Float16* gcWT0      = (_Float16*)carve((size_t)H * F * 2);
    _Float16* liWT0      = (_Float16*)carve((size_t)H * F * 2);
    _Float16* gcWT       = (_Float16*)carve((size_t)3 * H * H * 2);
    _Float16* liWT       = (_Float16*)carve((size_t)3 * H * H * 2);
    _Float16* outWT      = (_Float16*)carve((size_t)NC * H * L * 2);
    float*    lin        = (float*)   carve((size_t)N * H * 4);
    _Float16* hw         = (_Float16*)carve((size_t)N * H * 2);
    _Float16* jk_h       = (_Float16*)carve((size_t)N * H * L * 2);
    float*    out        = (float*)d_out;

    const int nbN = (N + 255) / 256;
    const int nbE = (E + 255) / 256;

    // 1) CSR build + dinv
    zero_i32<<<nbN, 256, 0, stream>>>(count, N);
    hist_dst<<<nbE, 256, 0, stream>>>(dst, count, E);
    make_dinv<<<nbN, 256, 0, stream>>>(count, dinv, N);
    scan_block<<<nbN, 256, 0, stream>>>(count, incl, blocksum, N);
    scan_top<<<1, 256, 0, stream>>>(blocksum, blockoff, nbN);
    make_rowptr<<<nbN, 256, 0, stream>>>(incl, count, blockoff, rowptr, cursor, N);
    scatter_perm<<<nbE, 256, 0, stream>>>(src, dst, dinv, cursor, sorted_src, sorted_nrm, E);

    // 2) casts (once per call)
    cast_f32_f16<<<(N * F / 4 + 255) / 256, 256, 0, stream>>>(x, xh, N * F / 4);
    transpose_cast<<<F, 256, 0, stream>>>(in_gc_W,  gcWT0, F, H);
    transpose_cast<<<F, 256, 0, stream>>>(in_lin_W, liWT0, F, H);
    for (int l = 0; l < 3; ++l) {
        transpose_cast<<<H, 256, 0, stream>>>(convs_W + (size_t)l * H * H, gcWT + (size_t)l * H * H, H, H);
        transpose_cast<<<H, 256, 0, stream>>>(lins_W  + (size_t)l * H * H, liWT + (size_t)l * H * H, H, H);
    }
    transpose_cast<<<H * L, 256, 0, stream>>>(out_W, outWT, H * L, NC);

    const dim3 ggrid((N + GBM - 1) / GBM, H / GBM);   // 391 x 2
    const dim3 ogrid((N + GBM - 1) / GBM, 1);
    const int agg_blocks = (N + 3) / 4;

    // 3) layers
    for (int l = 0; l < L; ++l) {
        const _Float16* Ah = (l == 0) ? xh : (jk_h + (size_t)(l - 1) * H);
        int lda            = (l == 0) ? F : H * L;
        int K              = (l == 0) ? F : H;
        const _Float16* gT = (l == 0) ? gcWT0 : (gcWT + (size_t)(l - 1) * H * H);
        const _Float16* lT = (l == 0) ? liWT0 : (liWT + (size_t)(l - 1) * H * H);
        const float* gcB   = (l == 0) ? in_gc_b  : (convs_b + (size_t)(l - 1) * H);
        const float* liB   = (l == 0) ? in_lin_b : (lins_b  + (size_t)(l - 1) * H);

        // lin <- A@lin_W + lin_b + gc_b  (fp32)
        gemm_f16<<<ggrid, 256, 0, stream>>>(Ah, lda, lT, liB, gcB, lin, nullptr, H, N, H, K);
        // hw <- A@gc_W  (fp16)
        gemm_f16<<<ggrid, 256, 0, stream>>>(Ah, lda, gT, nullptr, nullptr, nullptr, hw, H, N, H, K);
        // aggregate + self term + relu -> jk_h column l
        aggregate_csr<<<agg_blocks, 256, 0, stream>>>(rowptr, count, sorted_src, sorted_nrm,
                                                      dinv, hw, lin, jk_h + (size_t)l * H, N);
    }

    // 4) out = jk_h @ out_W + out_b (fp32 out, N=40 masked in 128-tile)
    gemm_f16<<<ogrid, 256, 0, stream>>>(jk_h, H * L, outWT, out_b, nullptr,
                                        out, nullptr, NC, N, NC, H * L);
}

// Round 4
// 746.486 us; speedup vs baseline: 5.3369x; 1.1278x over previous
//
#include <hip/hip_runtime.h>

typedef _Float16 half8 __attribute__((ext_vector_type(8)));
typedef _Float16 half4 __attribute__((ext_vector_type(4)));
typedef float floatx4 __attribute__((ext_vector_type(4)));

// async global->LDS, 16B per lane. LDS dest is wave-uniform base + lane*16.
__device__ __forceinline__ void gld16(const _Float16* g, _Float16* lds_base) {
    __builtin_amdgcn_global_load_lds(
        (const __attribute__((address_space(1))) unsigned int*)g,
        (__attribute__((address_space(3))) unsigned int*)lds_base,
        16, 0, 0);
}

// ---------------- small helpers ----------------
__global__ __launch_bounds__(256) void zero_i32(int* __restrict__ p, int n) {
    int i = blockIdx.x * 256 + threadIdx.x;
    if (i < n) p[i] = 0;
}

__global__ __launch_bounds__(256) void hist_dst(const int* __restrict__ dst,
                                                int* __restrict__ count, int E) {
    int e = blockIdx.x * 256 + threadIdx.x;
    if (e < E) atomicAdd(&count[dst[e]], 1);
}

__global__ __launch_bounds__(256) void make_dinv(const int* __restrict__ count,
                                                 float* __restrict__ dinv, int n) {
    int i = blockIdx.x * 256 + threadIdx.x;
    if (i < n) dinv[i] = rsqrtf(1.0f + (float)count[i]);
}

__global__ __launch_bounds__(256) void cast_f32_f16(const float* __restrict__ in,
                                                    _Float16* __restrict__ out, int n4) {
    int i = blockIdx.x * 256 + threadIdx.x;
    if (i < n4) {
        float4 v = *(const float4*)&in[(size_t)i * 4];
        half4 h = { (_Float16)v.x, (_Float16)v.y, (_Float16)v.z, (_Float16)v.w };
        *(half4*)&out[(size_t)i * 4] = h;
    }
}

// W[K x N] fp32 -> WT[N x K] fp16
__global__ __launch_bounds__(256) void transpose_cast(const float* __restrict__ W,
                                                      _Float16* __restrict__ WT,
                                                      int K, int N) {
    int k = blockIdx.x;
    int n = threadIdx.x;
    if (n < N) WT[(size_t)n * K + k] = (_Float16)W[(size_t)k * N + n];
}

// ---------------- scan for CSR ----------------
__global__ __launch_bounds__(256) void scan_block(const int* __restrict__ count,
                                                  int* __restrict__ incl,
                                                  int* __restrict__ blocksum, int n) {
    __shared__ int tmp[256];
    int t = threadIdx.x;
    int i = blockIdx.x * 256 + t;
    int v = (i < n) ? count[i] : 0;
    tmp[t] = v;
    __syncthreads();
    for (int off = 1; off < 256; off <<= 1) {
        int x = (t >= off) ? tmp[t - off] : 0;
        __syncthreads();
        tmp[t] += x;
        __syncthreads();
    }
    if (i < n) incl[i] = tmp[t];
    if (t == 255) blocksum[blockIdx.x] = tmp[255];
}

__global__ __launch_bounds__(256) void scan_top(const int* __restrict__ blocksum,
                                                int* __restrict__ blockoff, int nb) {
    __shared__ int tmp[256];
    int t = threadIdx.x;
    int v = (t < nb) ? blocksum[t] : 0;
    tmp[t] = v;
    __syncthreads();
    for (int off = 1; off < 256; off <<= 1) {
        int x = (t >= off) ? tmp[t - off] : 0;
        __syncthreads();
        tmp[t] += x;
        __syncthreads();
    }
    if (t < nb) blockoff[t] = tmp[t] - v;
}

__global__ __launch_bounds__(256) void make_rowptr(const int* __restrict__ incl,
                                                   const int* __restrict__ count,
                                                   const int* __restrict__ blockoff,
                                                   int* __restrict__ rowptr,
                                                   int* __restrict__ cursor, int n) {
    int i = blockIdx.x * 256 + threadIdx.x;
    if (i < n) {
        int r = incl[i] - count[i] + blockoff[blockIdx.x];
        rowptr[i] = r;
        cursor[i] = r;
    }
}

__global__ __launch_bounds__(256) void scatter_perm(const int* __restrict__ src,
                                                    const int* __restrict__ dst,
                                                    const float* __restrict__ dinv,
                                                    int* __restrict__ cursor,
                                                    int* __restrict__ sorted_src,
                                                    float* __restrict__ sorted_norm, int E) {
    int e = blockIdx.x * 256 + threadIdx.x;
    if (e < E) {
        int d = dst[e], s = src[e];
        int slot = atomicAdd(&cursor[d], 1);
        sorted_src[slot] = s;
        sorted_norm[slot] = dinv[s] * dinv[d];
    }
}

// ---------------- fp16 MFMA GEMM, global_load_lds staging, XOR-swizzled LDS ----
// C[M x Nrows] = A[M x K](lda) @ BT[Nrows x K]^T ; BM=BN=128, BK=64.
// 256 threads = 4 waves (2x2 of 64x64). 16x16x32 f16 MFMA, fp32 acc.
// DUAL: Nrows=512; cols<256 -> lin_h (+bias0+bias1), cols>=256 -> hw. fp16 out.
// !DUAL: fp32 out to Cf (+bias0), cols masked to Nrows.
template<bool DUAL>
__global__ __launch_bounds__(256) void gemm_mfma(
    const _Float16* __restrict__ A, int lda,
    const _Float16* __restrict__ BT, int Nrows,
    const float* __restrict__ bias0, const float* __restrict__ bias1,
    _Float16* __restrict__ lin_h, _Float16* __restrict__ hw,
    float* __restrict__ Cf, int ldc,
    int M, int K)
{
    __shared__ _Float16 As[128 * 64];
    __shared__ _Float16 Bs[128 * 64];

    const int tid  = threadIdx.x;
    const int wave = tid >> 6;
    const int lane = tid & 63;
    const int q    = lane >> 4;
    const int r    = lane & 15;

    const int wm = (wave & 1) * 64;
    const int wn = (wave >> 1) * 64;

    const int bn = blockIdx.x * 128;   // N-tile fastest: blocks sharing A co-resident
    const int bm = blockIdx.y * 128;

    const int srow  = wave * 32;       // rows this wave stages (per tile)
    const int lrow8 = lane >> 3;       // 0..7 row within 8-row chunk
    const int cp    = lane & 7;        // LDS chunk position 0..7

    floatx4 acc[4][4] = {};

    for (int k0 = 0; k0 < K; k0 += 64) {
        // stage: per wave 4 instrs A + 4 instrs B, each 8 rows x 128B.
        // source chunk swizzle c = cp ^ (row&7); LDS image row-major unpadded.
        #pragma unroll
        for (int t = 0; t < 4; ++t) {
            int lrow = srow + t * 8 + lrow8;
            int c    = cp ^ (lrow & 7);
            int gm = bm + lrow; if (gm > M - 1) gm = M - 1;
            gld16(&A[(size_t)gm * lda + k0 + c * 8], &As[(srow + t * 8) * 64]);
            int gn = bn + lrow; if (gn > Nrows - 1) gn = Nrows - 1;
            gld16(&BT[(size_t)gn * K + k0 + c * 8], &Bs[(srow + t * 8) * 64]);
        }
        __syncthreads();   // drains vmcnt (global_load_lds) + lgkm

        #pragma unroll
        for (int kk = 0; kk < 2; ++kk) {
            const int sc = ((kk << 2) | q) ^ (r & 7);   // swizzled chunk, uniform over mi/ni
            half8 af[4], bf[4];
            #pragma unroll
            for (int mi = 0; mi < 4; ++mi)
                af[mi] = *(const half8*)&As[(wm + mi * 16 + r) * 64 + sc * 8];
            #pragma unroll
            for (int ni = 0; ni < 4; ++ni)
                bf[ni] = *(const half8*)&Bs[(wn + ni * 16 + r) * 64 + sc * 8];
            #pragma unroll
            for (int mi = 0; mi < 4; ++mi)
                #pragma unroll
                for (int ni = 0; ni < 4; ++ni)
                    acc[mi][ni] = __builtin_amdgcn_mfma_f32_16x16x32_f16(
                        af[mi], bf[ni], acc[mi][ni], 0, 0, 0);
        }
        __syncthreads();
    }

    // epilogue: C/D layout col = r, row = q*4 + reg
    if (DUAL) {
        const bool islin = (bn < 256);                   // uniform per block
        _Float16* dstp = islin ? lin_h : hw;
        #pragma unroll
        for (int ni = 0; ni < 4; ++ni) {
            int col = bn + wn + ni * 16 + r;
            int c2  = islin ? col : col - 256;
            float badd = islin ? (bias0[col] + bias1[col]) : 0.0f;
            #pragma unroll
            for (int mi = 0; mi < 4; ++mi)
                #pragma unroll
                for (int reg = 0; reg < 4; ++reg) {
                    int gm = bm + wm + mi * 16 + q * 4 + reg;
                    if (gm < M)
                        dstp[(size_t)gm * 256 + c2] = (_Float16)(acc[mi][ni][reg] + badd);
                }
        }
    } else {
        #pragma unroll
        for (int ni = 0; ni < 4; ++ni) {
            int col = bn + wn + ni * 16 + r;
            if (col >= Nrows) continue;
            float badd = bias0 ? bias0[col] : 0.0f;
            #pragma unroll
            for (int mi = 0; mi < 4; ++mi)
                #pragma unroll
                for (int reg = 0; reg < 4; ++reg) {
                    int gm = bm + wm + mi * 16 + q * 4 + reg;
                    if (gm < M)
                        Cf[(size_t)gm * ldc + col] = acc[mi][ni][reg] + badd;
                }
        }
    }
}

// ---------------- fused CSR aggregate + self-loop + relu -> jk_h (fp16)
// wave per dst node, lane = 4 features; 4-deep gather pipeline.
__global__ __launch_bounds__(256) void aggregate_csr(
    const int* __restrict__ rowptr, const int* __restrict__ count,
    const int* __restrict__ sorted_src, const float* __restrict__ sorted_norm,
    const float* __restrict__ dinv,
    const _Float16* __restrict__ hw,
    const _Float16* __restrict__ lin_h,
    _Float16* __restrict__ jk_col, int n)
{
    int wave = (blockIdx.x * 256 + threadIdx.x) >> 6;
    int lane = threadIdx.x & 63;
    if (wave >= n) return;
    const int i = wave;

    const int start = rowptr[i];
    const int deg   = count[i];

    half4 l4 = *(const half4*)&lin_h[(size_t)i * 256 + lane * 4];
    float4 acc = make_float4((float)l4[0], (float)l4[1], (float)l4[2], (float)l4[3]);

    for (int base = 0; base < deg; base += 64) {
        int m = deg - base;
        if (m > 64) m = 64;
        int   s_l  = 0;
        float nm_l = 0.0f;
        if (lane < m) {
            s_l  = sorted_src[start + base + lane];
            nm_l = sorted_norm[start + base + lane];
        }
        for (int j = 0; j < m; j += 4) {
            half4 hv[4];
            float nm[4];
            #pragma unroll
            for (int k2 = 0; k2 < 4; ++k2) {
                int jj  = j + k2;
                int idx = (jj < m) ? jj : (m - 1);
                int s   = __shfl(s_l, idx, 64);
                nm[k2]  = (jj < m) ? __shfl(nm_l, jj, 64) : 0.0f;
                hv[k2]  = *(const half4*)&hw[(size_t)s * 256 + lane * 4];
            }
            #pragma unroll
            for (int k2 = 0; k2 < 4; ++k2) {
                acc.x = fmaf((float)hv[k2][0], nm[k2], acc.x);
                acc.y = fmaf((float)hv[k2][1], nm[k2], acc.y);
                acc.z = fmaf((float)hv[k2][2], nm[k2], acc.z);
                acc.w = fmaf((float)hv[k2][3], nm[k2], acc.w);
            }
        }
    }

    float di = dinv[i];
    float sn = di * di;
    half4 hs = *(const half4*)&hw[(size_t)i * 256 + lane * 4];
    acc.x = fmaxf(fmaf((float)hs[0], sn, acc.x), 0.0f);
    acc.y = fmaxf(fmaf((float)hs[1], sn, acc.y), 0.0f);
    acc.z = fmaxf(fmaf((float)hs[2], sn, acc.z), 0.0f);
    acc.w = fmaxf(fmaf((float)hs[3], sn, acc.w), 0.0f);

    half4 o = { (_Float16)acc.x, (_Float16)acc.y, (_Float16)acc.z, (_Float16)acc.w };
    *(half4*)&jk_col[(size_t)i * 1024 + lane * 4] = o;
}

extern "C" void kernel_launch(void* const* d_in, const int* in_sizes, int n_in,
                              void* d_out, int out_size, void* d_ws, size_t ws_size,
                              hipStream_t stream) {
    const float* x        = (const float*)d_in[0];
    const int*   ei       = (const int*)d_in[1];
    const float* in_gc_W  = (const float*)d_in[2];
    const float* in_gc_b  = (const float*)d_in[3];
    const float* in_lin_W = (const float*)d_in[4];
    const float* in_lin_b = (const float*)d_in[5];
    const float* convs_W  = (const float*)d_in[6];
    const float* convs_b  = (const float*)d_in[7];
    const float* lins_W   = (const float*)d_in[8];
    const float* lins_b   = (const float*)d_in[9];
    const float* out_W    = (const float*)d_in[10];
    const float* out_b    = (const float*)d_in[11];

    const int N = 50000;
    const int E = in_sizes[1] / 2;
    const int F = 512, H = 256, L = 4, NC = 40;

    const int* src = ei;
    const int* dst = ei + E;

    char* ws = (char*)d_ws;
    auto carve = [&](size_t bytes) { void* p = ws; ws += (bytes + 255) & ~(size_t)255; return p; };
    float*    dinv       = (float*)carve((size_t)N * 4);
    int*      count      = (int*)  carve((size_t)N * 4);
    int*      incl       = (int*)  carve((size_t)N * 4);
    int*      rowptr     = (int*)  carve((size_t)N * 4);
    int*      cursor     = (int*)  carve((size_t)N * 4);
    int*      blocksum   = (int*)  carve(256 * 4);
    int*      blockoff   = (int*)  carve(256 * 4);
    int*      sorted_src = (int*)  carve((size_t)E * 4);
    float*    sorted_nrm = (float*)carve((size_t)E * 4);
    _Float16* xh         = (_Float16*)carve((size_t)N * F * 2);
    // layer-0 combined: [512 rows x 512] = liWT0 rows 0-255, gcWT0 rows 256-511
    _Float16* w0comb     = (_Float16*)carve((size_t)512 * F * 2);
    // layers 1-3 combined: 3 x [512 rows x 256]
    _Float16* wcomb      = (_Float16*)carve((size_t)3 * 512 * H * 2);
    _Float16* outWT      = (_Float16*)carve((size_t)NC * H * L * 2);
    _Float16* lin_h      = (_Float16*)carve((size_t)N * H * 2);
    _Float16* hw         = (_Float16*)carve((size_t)N * H * 2);
    _Float16* jk_h       = (_Float16*)carve((size_t)N * H * L * 2);
    float*    out        = (float*)d_out;

    const int nbN = (N + 255) / 256;
    const int nbE = (E + 255) / 256;

    // 1) CSR build + dinv
    zero_i32<<<nbN, 256, 0, stream>>>(count, N);
    hist_dst<<<nbE, 256, 0, stream>>>(dst, count, E);
    make_dinv<<<nbN, 256, 0, stream>>>(count, dinv, N);
    scan_block<<<nbN, 256, 0, stream>>>(count, incl, blocksum, N);
    scan_top<<<1, 256, 0, stream>>>(blocksum, blockoff, nbN);
    make_rowptr<<<nbN, 256, 0, stream>>>(incl, count, blockoff, rowptr, cursor, N);
    scatter_perm<<<nbE, 256, 0, stream>>>(src, dst, dinv, cursor, sorted_src, sorted_nrm, E);

    // 2) casts / transposes
    cast_f32_f16<<<(N * F / 4 + 255) / 256, 256, 0, stream>>>(x, xh, N * F / 4);
    transpose_cast<<<F, 256, 0, stream>>>(in_lin_W, w0comb,               F, H);  // rows 0-255
    transpose_cast<<<F, 256, 0, stream>>>(in_gc_W,  w0comb + (size_t)H * F, F, H); // rows 256-511
    for (int l = 0; l < 3; ++l) {
        _Float16* wl = wcomb + (size_t)l * 512 * H;
        transpose_cast<<<H, 256, 0, stream>>>(lins_W  + (size_t)l * H * H, wl,                   H, H);
        transpose_cast<<<H, 256, 0, stream>>>(convs_W + (size_t)l * H * H, wl + (size_t)H * H,   H, H);
    }
    transpose_cast<<<H * L, 256, 0, stream>>>(out_W, outWT, H * L, NC);

    const dim3 dgrid(4, (N + 127) / 128);   // N-tiles fastest (A reuse in L2)
    const dim3 ogrid(1, (N + 127) / 128);
    const int agg_blocks = (N + 3) / 4;

    // 3) layers
    for (int l = 0; l < L; ++l) {
        const _Float16* Ah = (l == 0) ? xh : (jk_h + (size_t)(l - 1) * H);
        int lda            = (l == 0) ? F : H * L;
        int K              = (l == 0) ? F : H;
        const _Float16* BT = (l == 0) ? w0comb : (wcomb + (size_t)(l - 1) * 512 * H);
        const float* gcB   = (l == 0) ? in_gc_b  : (convs_b + (size_t)(l - 1) * H);
        const float* liB   = (l == 0) ? in_lin_b : (lins_b  + (size_t)(l - 1) * H);

        gemm_mfma<true><<<dgrid, 256, 0, stream>>>(Ah, lda, BT, 512, liB, gcB,
                                                   lin_h, hw, nullptr, 0, N, K);
        aggregate_csr<<<agg_blocks, 256, 0, stream>>>(rowptr, count, sorted_src, sorted_nrm,
                                                      dinv, hw, lin_h, jk_h + (size_t)l * H, N);
    }

    // 4) out = jk_h @ out_W + out_b
    gemm_mfma<false><<<ogrid, 256, 0, stream>>>(jk_h, H * L, outWT, NC, out_b, nullptr,
                                                nullptr, nullptr, out, NC, N, H * L);
}

// Round 5
// 740.889 us; speedup vs baseline: 5.3772x; 1.0076x over previous
//
#include <hip/hip_runtime.h>

typedef _Float16 half8 __attribute__((ext_vector_type(8)));
typedef _Float16 half4 __attribute__((ext_vector_type(4)));
typedef float floatx4 __attribute__((ext_vector_type(4)));

// async global->LDS, 16B per lane. LDS dest is wave-uniform base + lane*16.
__device__ __forceinline__ void gld16(const _Float16* g, _Float16* lds_base) {
    __builtin_amdgcn_global_load_lds(
        (const __attribute__((address_space(1))) unsigned int*)g,
        (__attribute__((address_space(3))) unsigned int*)lds_base,
        16, 0, 0);
}

// ---------------- small helpers ----------------
__global__ __launch_bounds__(256) void zero_i32(int* __restrict__ p, int n) {
    int i = blockIdx.x * 256 + threadIdx.x;
    if (i < n) p[i] = 0;
}

__global__ __launch_bounds__(256) void hist_dst(const int* __restrict__ dst,
                                                int* __restrict__ count, int E) {
    int e = blockIdx.x * 256 + threadIdx.x;
    if (e < E) atomicAdd(&count[dst[e]], 1);
}

__global__ __launch_bounds__(256) void cast_f32_f16(const float* __restrict__ in,
                                                    _Float16* __restrict__ out, int n4) {
    int i = blockIdx.x * 256 + threadIdx.x;
    if (i < n4) {
        float4 v = *(const float4*)&in[(size_t)i * 4];
        half4 h = { (_Float16)v.x, (_Float16)v.y, (_Float16)v.z, (_Float16)v.w };
        *(half4*)&out[(size_t)i * 4] = h;
    }
}

// tiled transpose+cast: W[K x N] fp32 -> WT[N x K] fp16. 32x32 tiles via LDS.
// Coalesced global reads (along n) AND coalesced global writes (along k).
__global__ __launch_bounds__(256) void transpose_cast_tiled(
    const float* __restrict__ W, _Float16* __restrict__ WT, int K, int N)
{
    __shared__ _Float16 t[32][33];
    const int k0 = blockIdx.x * 32, n0 = blockIdx.y * 32;
    const int tx = threadIdx.x & 31, ty = threadIdx.x >> 5;   // ty 0..7
    #pragma unroll
    for (int i = 0; i < 4; ++i) {
        int k = k0 + ty + i * 8, n = n0 + tx;
        float v = (k < K && n < N) ? W[(size_t)k * N + n] : 0.0f;
        t[ty + i * 8][tx] = (_Float16)v;
    }
    __syncthreads();
    #pragma unroll
    for (int i = 0; i < 4; ++i) {
        int n = n0 + ty + i * 8, k = k0 + tx;
        if (n < N && k < K) WT[(size_t)n * K + k] = t[tx][ty + i * 8];
    }
}

// ---------------- scan for CSR (also emits dinv) ----------------
__global__ __launch_bounds__(256) void scan_block(const int* __restrict__ count,
                                                  int* __restrict__ incl,
                                                  int* __restrict__ blocksum,
                                                  float* __restrict__ dinv, int n) {
    __shared__ int tmp[256];
    int t = threadIdx.x;
    int i = blockIdx.x * 256 + t;
    int v = (i < n) ? count[i] : 0;
    if (i < n) dinv[i] = rsqrtf(1.0f + (float)v);
    tmp[t] = v;
    __syncthreads();
    for (int off = 1; off < 256; off <<= 1) {
        int x = (t >= off) ? tmp[t - off] : 0;
        __syncthreads();
        tmp[t] += x;
        __syncthreads();
    }
    if (i < n) incl[i] = tmp[t];
    if (t == 255) blocksum[blockIdx.x] = tmp[255];
}

__global__ __launch_bounds__(256) void scan_top(const int* __restrict__ blocksum,
                                                int* __restrict__ blockoff, int nb) {
    __shared__ int tmp[256];
    int t = threadIdx.x;
    int v = (t < nb) ? blocksum[t] : 0;
    tmp[t] = v;
    __syncthreads();
    for (int off = 1; off < 256; off <<= 1) {
        int x = (t >= off) ? tmp[t - off] : 0;
        __syncthreads();
        tmp[t] += x;
        __syncthreads();
    }
    if (t < nb) blockoff[t] = tmp[t] - v;
}

__global__ __launch_bounds__(256) void make_rowptr(const int* __restrict__ incl,
                                                   const int* __restrict__ count,
                                                   const int* __restrict__ blockoff,
                                                   int* __restrict__ rowptr,
                                                   int* __restrict__ cursor, int n) {
    int i = blockIdx.x * 256 + threadIdx.x;
    if (i < n) {
        int r = incl[i] - count[i] + blockoff[blockIdx.x];
        rowptr[i] = r;
        cursor[i] = r;
    }
}

// packed (src, norm) -> one 8B store per edge
__global__ __launch_bounds__(256) void scatter_perm(const int* __restrict__ src,
                                                    const int* __restrict__ dst,
                                                    const float* __restrict__ dinv,
                                                    int* __restrict__ cursor,
                                                    int2* __restrict__ sorted_meta, int E) {
    int e = blockIdx.x * 256 + threadIdx.x;
    if (e < E) {
        int d = dst[e], s = src[e];
        int slot = atomicAdd(&cursor[d], 1);
        sorted_meta[slot] = make_int2(s, __float_as_int(dinv[s] * dinv[d]));
    }
}

// ---------------- fp16 MFMA GEMM, global_load_lds staging, XOR-swizzled LDS ----
template<bool DUAL>
__global__ __launch_bounds__(256) void gemm_mfma(
    const _Float16* __restrict__ A, int lda,
    const _Float16* __restrict__ BT, int Nrows,
    const float* __restrict__ bias0, const float* __restrict__ bias1,
    _Float16* __restrict__ lin_h, _Float16* __restrict__ hw,
    float* __restrict__ Cf, int ldc,
    int M, int K)
{
    __shared__ _Float16 As[128 * 64];
    __shared__ _Float16 Bs[128 * 64];

    const int tid  = threadIdx.x;
    const int wave = tid >> 6;
    const int lane = tid & 63;
    const int q    = lane >> 4;
    const int r    = lane & 15;

    const int wm = (wave & 1) * 64;
    const int wn = (wave >> 1) * 64;

    const int bn = blockIdx.x * 128;
    const int bm = blockIdx.y * 128;

    const int srow  = wave * 32;
    const int lrow8 = lane >> 3;
    const int cp    = lane & 7;

    floatx4 acc[4][4] = {};

    for (int k0 = 0; k0 < K; k0 += 64) {
        #pragma unroll
        for (int t = 0; t < 4; ++t) {
            int lrow = srow + t * 8 + lrow8;
            int c    = cp ^ (lrow & 7);
            int gm = bm + lrow; if (gm > M - 1) gm = M - 1;
            gld16(&A[(size_t)gm * lda + k0 + c * 8], &As[(srow + t * 8) * 64]);
            int gn = bn + lrow; if (gn > Nrows - 1) gn = Nrows - 1;
            gld16(&BT[(size_t)gn * K + k0 + c * 8], &Bs[(srow + t * 8) * 64]);
        }
        __syncthreads();

        #pragma unroll
        for (int kk = 0; kk < 2; ++kk) {
            const int sc = ((kk << 2) | q) ^ (r & 7);
            half8 af[4], bf[4];
            #pragma unroll
            for (int mi = 0; mi < 4; ++mi)
                af[mi] = *(const half8*)&As[(wm + mi * 16 + r) * 64 + sc * 8];
            #pragma unroll
            for (int ni = 0; ni < 4; ++ni)
                bf[ni] = *(const half8*)&Bs[(wn + ni * 16 + r) * 64 + sc * 8];
            #pragma unroll
            for (int mi = 0; mi < 4; ++mi)
                #pragma unroll
                for (int ni = 0; ni < 4; ++ni)
                    acc[mi][ni] = __builtin_amdgcn_mfma_f32_16x16x32_f16(
                        af[mi], bf[ni], acc[mi][ni], 0, 0, 0);
        }
        __syncthreads();
    }

    if (DUAL) {
        const bool islin = (bn < 256);
        _Float16* dstp = islin ? lin_h : hw;
        #pragma unroll
        for (int ni = 0; ni < 4; ++ni) {
            int col = bn + wn + ni * 16 + r;
            int c2  = islin ? col : col - 256;
            float badd = islin ? (bias0[col] + bias1[col]) : 0.0f;
            #pragma unroll
            for (int mi = 0; mi < 4; ++mi)
                #pragma unroll
                for (int reg = 0; reg < 4; ++reg) {
                    int gm = bm + wm + mi * 16 + q * 4 + reg;
                    if (gm < M)
                        dstp[(size_t)gm * 256 + c2] = (_Float16)(acc[mi][ni][reg] + badd);
                }
        }
    } else {
        #pragma unroll
        for (int ni = 0; ni < 4; ++ni) {
            int col = bn + wn + ni * 16 + r;
            if (col >= Nrows) continue;
            float badd = bias0 ? bias0[col] : 0.0f;
            #pragma unroll
            for (int mi = 0; mi < 4; ++mi)
                #pragma unroll
                for (int reg = 0; reg < 4; ++reg) {
                    int gm = bm + wm + mi * 16 + q * 4 + reg;
                    if (gm < M)
                        Cf[(size_t)gm * ldc + col] = acc[mi][ni][reg] + badd;
                }
        }
    }
}

// ---------------- fused CSR aggregate + self-loop + relu -> jk_h (fp16)
// wave per dst node. Half-wave h (32 lanes) processes one edge; lane covers
// 8 features (16B half8 loads). 4-deep unroll x 2 halves = 8 edges in flight.
__global__ __launch_bounds__(256) void aggregate_csr(
    const int* __restrict__ rowptr, const int* __restrict__ count,
    const int2* __restrict__ sorted_meta,
    const float* __restrict__ dinv,
    const _Float16* __restrict__ hw,
    const _Float16* __restrict__ lin_h,
    _Float16* __restrict__ jk_col, int n)
{
    int wave = (blockIdx.x * 256 + threadIdx.x) >> 6;
    int lane = threadIdx.x & 63;
    if (wave >= n) return;
    const int i = wave;
    const int h  = lane >> 5;    // half-wave id
    const int fl = lane & 31;    // feature group: 8 halves

    const int start = rowptr[i];
    const int deg   = count[i];

    float accf[8];
    if (h == 0) {
        half8 l8 = *(const half8*)&lin_h[(size_t)i * 256 + fl * 8];
        #pragma unroll
        for (int t = 0; t < 8; ++t) accf[t] = (float)l8[t];
    } else {
        float di = dinv[i];
        float sn = di * di;
        half8 s8 = *(const half8*)&hw[(size_t)i * 256 + fl * 8];
        #pragma unroll
        for (int t = 0; t < 8; ++t) accf[t] = (float)s8[t] * sn;
    }

    for (int base = 0; base < deg; base += 64) {
        int m = deg - base;
        if (m > 64) m = 64;
        int2 meta = make_int2(0, 0);
        if (lane < m) meta = sorted_meta[start + base + lane];

        for (int j = 0; j < m; j += 8) {
            half8 hv[4];
            float nm[4];
            #pragma unroll
            for (int k2 = 0; k2 < 4; ++k2) {
                int e   = j + k2 * 2 + h;
                int idx = (e < m) ? e : (m - 1);
                int s   = __shfl(meta.x, idx, 64);
                int nmb = __shfl(meta.y, idx, 64);
                nm[k2]  = (e < m) ? __int_as_float(nmb) : 0.0f;
                hv[k2]  = *(const half8*)&hw[(size_t)s * 256 + fl * 8];
            }
            #pragma unroll
            for (int k2 = 0; k2 < 4; ++k2)
                #pragma unroll
                for (int t = 0; t < 8; ++t)
                    accf[t] = fmaf((float)hv[k2][t], nm[k2], accf[t]);
        }
    }

    // combine half-waves (lane L and L+32 hold partial sums of same features)
    #pragma unroll
    for (int t = 0; t < 8; ++t)
        accf[t] += __shfl_xor(accf[t], 32, 64);

    if (h == 0) {
        half8 o;
        #pragma unroll
        for (int t = 0; t < 8; ++t) o[t] = (_Float16)fmaxf(accf[t], 0.0f);
        *(half8*)&jk_col[(size_t)i * 1024 + fl * 8] = o;
    }
}

extern "C" void kernel_launch(void* const* d_in, const int* in_sizes, int n_in,
                              void* d_out, int out_size, void* d_ws, size_t ws_size,
                              hipStream_t stream) {
    const float* x        = (const float*)d_in[0];
    const int*   ei       = (const int*)d_in[1];
    const float* in_gc_W  = (const float*)d_in[2];
    const float* in_gc_b  = (const float*)d_in[3];
    const float* in_lin_W = (const float*)d_in[4];
    const float* in_lin_b = (const float*)d_in[5];
    const float* convs_W  = (const float*)d_in[6];
    const float* convs_b  = (const float*)d_in[7];
    const float* lins_W   = (const float*)d_in[8];
    const float* lins_b   = (const float*)d_in[9];
    const float* out_W    = (const float*)d_in[10];
    const float* out_b    = (const float*)d_in[11];

    const int N = 50000;
    const int E = in_sizes[1] / 2;
    const int F = 512, H = 256, L = 4, NC = 40;

    const int* src = ei;
    const int* dst = ei + E;

    char* ws = (char*)d_ws;
    auto carve = [&](size_t bytes) { void* p = ws; ws += (bytes + 255) & ~(size_t)255; return p; };
    float*    dinv        = (float*)carve((size_t)N * 4);
    int*      count       = (int*)  carve((size_t)N * 4);
    int*      incl        = (int*)  carve((size_t)N * 4);
    int*      rowptr      = (int*)  carve((size_t)N * 4);
    int*      cursor      = (int*)  carve((size_t)N * 4);
    int*      blocksum    = (int*)  carve(256 * 4);
    int*      blockoff    = (int*)  carve(256 * 4);
    int2*     sorted_meta = (int2*) carve((size_t)E * 8);
    _Float16* xh          = (_Float16*)carve((size_t)N * F * 2);
    _Float16* w0comb      = (_Float16*)carve((size_t)512 * F * 2);
    _Float16* wcomb       = (_Float16*)carve((size_t)3 * 512 * H * 2);
    _Float16* outWT       = (_Float16*)carve((size_t)NC * H * L * 2);
    _Float16* lin_h       = (_Float16*)carve((size_t)N * H * 2);
    _Float16* hw          = (_Float16*)carve((size_t)N * H * 2);
    _Float16* jk_h        = (_Float16*)carve((size_t)N * H * L * 2);
    float*    out         = (float*)d_out;

    const int nbN = (N + 255) / 256;
    const int nbE = (E + 255) / 256;

    // 1) CSR build + dinv
    zero_i32<<<nbN, 256, 0, stream>>>(count, N);
    hist_dst<<<nbE, 256, 0, stream>>>(dst, count, E);
    scan_block<<<nbN, 256, 0, stream>>>(count, incl, blocksum, dinv, N);
    scan_top<<<1, 256, 0, stream>>>(blocksum, blockoff, nbN);
    make_rowptr<<<nbN, 256, 0, stream>>>(incl, count, blockoff, rowptr, cursor, N);
    scatter_perm<<<nbE, 256, 0, stream>>>(src, dst, dinv, cursor, sorted_meta, E);

    // 2) casts / tiled transposes
    cast_f32_f16<<<(N * F / 4 + 255) / 256, 256, 0, stream>>>(x, xh, N * F / 4);
    {
        dim3 tg((F + 31) / 32, (H + 31) / 32);
        transpose_cast_tiled<<<tg, 256, 0, stream>>>(in_lin_W, w0comb,                F, H);
        transpose_cast_tiled<<<tg, 256, 0, stream>>>(in_gc_W,  w0comb + (size_t)H * F, F, H);
        dim3 th((H + 31) / 32, (H + 31) / 32);
        for (int l = 0; l < 3; ++l) {
            _Float16* wl = wcomb + (size_t)l * 512 * H;
            transpose_cast_tiled<<<th, 256, 0, stream>>>(lins_W  + (size_t)l * H * H, wl,                 H, H);
            transpose_cast_tiled<<<th, 256, 0, stream>>>(convs_W + (size_t)l * H * H, wl + (size_t)H * H, H, H);
        }
        dim3 to((H * L + 31) / 32, (NC + 31) / 32);
        transpose_cast_tiled<<<to, 256, 0, stream>>>(out_W, outWT, H * L, NC);
    }

    const dim3 dgrid(4, (N + 127) / 128);
    const dim3 ogrid(1, (N + 127) / 128);
    const int agg_blocks = (N + 3) / 4;

    // 3) layers
    for (int l = 0; l < L; ++l) {
        const _Float16* Ah = (l == 0) ? xh : (jk_h + (size_t)(l - 1) * H);
        int lda            = (l == 0) ? F : H * L;
        int K              = (l == 0) ? F : H;
        const _Float16* BT = (l == 0) ? w0comb : (wcomb + (size_t)(l - 1) * 512 * H);
        const float* gcB   = (l == 0) ? in_gc_b  : (convs_b + (size_t)(l - 1) * H);
        const float* liB   = (l == 0) ? in_lin_b : (lins_b  + (size_t)(l - 1) * H);

        gemm_mfma<true><<<dgrid, 256, 0, stream>>>(Ah, lda, BT, 512, liB, gcB,
                                                   lin_h, hw, nullptr, 0, N, K);
        aggregate_csr<<<agg_blocks, 256, 0, stream>>>(rowptr, count, sorted_meta,
                                                      dinv, hw, lin_h, jk_h + (size_t)l * H, N);
    }

    // 4) out = jk_h @ out_W + out_b
    gemm_mfma<false><<<ogrid, 256, 0, stream>>>(jk_h, H * L, outWT, NC, out_b, nullptr,
                                                nullptr, nullptr, out, NC, N, H * L);
}

// Round 6
// 725.821 us; speedup vs baseline: 5.4888x; 1.0208x over previous
//
#include <hip/hip_runtime.h>

typedef _Float16 half8 __attribute__((ext_vector_type(8)));
typedef _Float16 half4 __attribute__((ext_vector_type(4)));
typedef float floatx4 __attribute__((ext_vector_type(4)));

// async global->LDS, 16B per lane. LDS dest is wave-uniform base + lane*16.
__device__ __forceinline__ void gld16(const _Float16* g, _Float16* lds_base) {
    __builtin_amdgcn_global_load_lds(
        (const __attribute__((address_space(1))) unsigned int*)g,
        (__attribute__((address_space(3))) unsigned int*)lds_base,
        16, 0, 0);
}

// ---------------- small helpers ----------------
__global__ __launch_bounds__(256) void zero_i32(int* __restrict__ p, int n) {
    int i = blockIdx.x * 256 + threadIdx.x;
    if (i < n) p[i] = 0;
}

__global__ __launch_bounds__(256) void hist_dst(const int* __restrict__ dst,
                                                int* __restrict__ count, int E) {
    int e = blockIdx.x * 256 + threadIdx.x;
    if (e < E) atomicAdd(&count[dst[e]], 1);
}

__global__ __launch_bounds__(256) void cast_f32_f16(const float* __restrict__ in,
                                                    _Float16* __restrict__ out, int n4) {
    int i = blockIdx.x * 256 + threadIdx.x;
    if (i < n4) {
        float4 v = *(const float4*)&in[(size_t)i * 4];
        half4 h = { (_Float16)v.x, (_Float16)v.y, (_Float16)v.z, (_Float16)v.w };
        *(half4*)&out[(size_t)i * 4] = h;
    }
}

// tiled transpose+cast: W[K x N] fp32 -> WT[N x K] fp16. 32x32 tiles via LDS.
__global__ __launch_bounds__(256) void transpose_cast_tiled(
    const float* __restrict__ W, _Float16* __restrict__ WT, int K, int N)
{
    __shared__ _Float16 t[32][33];
    const int k0 = blockIdx.x * 32, n0 = blockIdx.y * 32;
    const int tx = threadIdx.x & 31, ty = threadIdx.x >> 5;
    #pragma unroll
    for (int i = 0; i < 4; ++i) {
        int k = k0 + ty + i * 8, n = n0 + tx;
        float v = (k < K && n < N) ? W[(size_t)k * N + n] : 0.0f;
        t[ty + i * 8][tx] = (_Float16)v;
    }
    __syncthreads();
    #pragma unroll
    for (int i = 0; i < 4; ++i) {
        int n = n0 + ty + i * 8, k = k0 + tx;
        if (n < N && k < K) WT[(size_t)n * K + k] = t[tx][ty + i * 8];
    }
}

// ---------------- scan for CSR (also emits dinv) ----------------
__global__ __launch_bounds__(256) void scan_block(const int* __restrict__ count,
                                                  int* __restrict__ incl,
                                                  int* __restrict__ blocksum,
                                                  float* __restrict__ dinv, int n) {
    __shared__ int tmp[256];
    int t = threadIdx.x;
    int i = blockIdx.x * 256 + t;
    int v = (i < n) ? count[i] : 0;
    if (i < n) dinv[i] = rsqrtf(1.0f + (float)v);
    tmp[t] = v;
    __syncthreads();
    for (int off = 1; off < 256; off <<= 1) {
        int x = (t >= off) ? tmp[t - off] : 0;
        __syncthreads();
        tmp[t] += x;
        __syncthreads();
    }
    if (i < n) incl[i] = tmp[t];
    if (t == 255) blocksum[blockIdx.x] = tmp[255];
}

__global__ __launch_bounds__(256) void scan_top(const int* __restrict__ blocksum,
                                                int* __restrict__ blockoff, int nb) {
    __shared__ int tmp[256];
    int t = threadIdx.x;
    int v = (t < nb) ? blocksum[t] : 0;
    tmp[t] = v;
    __syncthreads();
    for (int off = 1; off < 256; off <<= 1) {
        int x = (t >= off) ? tmp[t - off] : 0;
        __syncthreads();
        tmp[t] += x;
        __syncthreads();
    }
    if (t < nb) blockoff[t] = tmp[t] - v;
}

__global__ __launch_bounds__(256) void make_rowptr(const int* __restrict__ incl,
                                                   const int* __restrict__ count,
                                                   const int* __restrict__ blockoff,
                                                   int* __restrict__ rowptr,
                                                   int* __restrict__ cursor, int n) {
    int i = blockIdx.x * 256 + threadIdx.x;
    if (i < n) {
        int r = incl[i] - count[i] + blockoff[blockIdx.x];
        rowptr[i] = r;
        cursor[i] = r;
    }
}

// packed (src, norm) -> one 8B store per edge
__global__ __launch_bounds__(256) void scatter_perm(const int* __restrict__ src,
                                                    const int* __restrict__ dst,
                                                    const float* __restrict__ dinv,
                                                    int* __restrict__ cursor,
                                                    int2* __restrict__ sorted_meta, int E) {
    int e = blockIdx.x * 256 + threadIdx.x;
    if (e < E) {
        int d = dst[e], s = src[e];
        int slot = atomicAdd(&cursor[d], 1);
        sorted_meta[slot] = make_int2(s, __float_as_int(dinv[s] * dinv[d]));
    }
}

// ---------------- fp16 MFMA GEMM, global_load_lds staging, XOR-swizzled LDS ----
template<bool DUAL>
__global__ __launch_bounds__(256) void gemm_mfma(
    const _Float16* __restrict__ A, int lda,
    const _Float16* __restrict__ BT, int Nrows,
    const float* __restrict__ bias0, const float* __restrict__ bias1,
    _Float16* __restrict__ lin_h, _Float16* __restrict__ hw,
    float* __restrict__ Cf, int ldc,
    int M, int K)
{
    __shared__ _Float16 As[128 * 64];
    __shared__ _Float16 Bs[128 * 64];

    const int tid  = threadIdx.x;
    const int wave = tid >> 6;
    const int lane = tid & 63;
    const int q    = lane >> 4;
    const int r    = lane & 15;

    const int wm = (wave & 1) * 64;
    const int wn = (wave >> 1) * 64;

    const int bn = blockIdx.x * 128;
    const int bm = blockIdx.y * 128;

    const int srow  = wave * 32;
    const int lrow8 = lane >> 3;
    const int cp    = lane & 7;

    floatx4 acc[4][4] = {};

    for (int k0 = 0; k0 < K; k0 += 64) {
        #pragma unroll
        for (int t = 0; t < 4; ++t) {
            int lrow = srow + t * 8 + lrow8;
            int c    = cp ^ (lrow & 7);
            int gm = bm + lrow; if (gm > M - 1) gm = M - 1;
            gld16(&A[(size_t)gm * lda + k0 + c * 8], &As[(srow + t * 8) * 64]);
            int gn = bn + lrow; if (gn > Nrows - 1) gn = Nrows - 1;
            gld16(&BT[(size_t)gn * K + k0 + c * 8], &Bs[(srow + t * 8) * 64]);
        }
        __syncthreads();

        #pragma unroll
        for (int kk = 0; kk < 2; ++kk) {
            const int sc = ((kk << 2) | q) ^ (r & 7);
            half8 af[4], bf[4];
            #pragma unroll
            for (int mi = 0; mi < 4; ++mi)
                af[mi] = *(const half8*)&As[(wm + mi * 16 + r) * 64 + sc * 8];
            #pragma unroll
            for (int ni = 0; ni < 4; ++ni)
                bf[ni] = *(const half8*)&Bs[(wn + ni * 16 + r) * 64 + sc * 8];
            #pragma unroll
            for (int mi = 0; mi < 4; ++mi)
                #pragma unroll
                for (int ni = 0; ni < 4; ++ni)
                    acc[mi][ni] = __builtin_amdgcn_mfma_f32_16x16x32_f16(
                        af[mi], bf[ni], acc[mi][ni], 0, 0, 0);
        }
        __syncthreads();
    }

    if (DUAL) {
        const bool islin = (bn < 256);
        _Float16* dstp = islin ? lin_h : hw;
        #pragma unroll
        for (int ni = 0; ni < 4; ++ni) {
            int col = bn + wn + ni * 16 + r;
            int c2  = islin ? col : col - 256;
            float badd = islin ? (bias0[col] + bias1[col]) : 0.0f;
            #pragma unroll
            for (int mi = 0; mi < 4; ++mi)
                #pragma unroll
                for (int reg = 0; reg < 4; ++reg) {
                    int gm = bm + wm + mi * 16 + q * 4 + reg;
                    if (gm < M)
                        dstp[(size_t)gm * 256 + c2] = (_Float16)(acc[mi][ni][reg] + badd);
                }
        }
    } else {
        #pragma unroll
        for (int ni = 0; ni < 4; ++ni) {
            int col = bn + wn + ni * 16 + r;
            if (col >= Nrows) continue;
            float badd = bias0 ? bias0[col] : 0.0f;
            #pragma unroll
            for (int mi = 0; mi < 4; ++mi)
                #pragma unroll
                for (int reg = 0; reg < 4; ++reg) {
                    int gm = bm + wm + mi * 16 + q * 4 + reg;
                    if (gm < M)
                        Cf[(size_t)gm * ldc + col] = acc[mi][ni][reg] + badd;
                }
        }
    }
}

// ---------------- fused CSR aggregate, feature-split across XCDs ----------------
// Each block handles 4 nodes x ONE 128-feature half. blockIdx%8 -> XCD slot
// (round-robin heuristic): slots 0-3 take half 0, slots 4-7 take half 1, so each
// XCD's L2 only streams 12.8 MB of hw instead of 25.6 MB.
// Within a wave: quarter-wave (16 lanes x half8 = 256B) per edge, 4 edges
// concurrent x 4-deep unroll = 16 edges in flight.
__global__ __launch_bounds__(256) void aggregate_csr(
    const int* __restrict__ rowptr, const int* __restrict__ count,
    const int2* __restrict__ sorted_meta,
    const float* __restrict__ dinv,
    const _Float16* __restrict__ hw,
    const _Float16* __restrict__ lin_h,
    _Float16* __restrict__ jk_col, int n)
{
    const int bx    = blockIdx.x;
    const int xslot = bx & 7;
    const int half  = xslot >> 2;                       // 0 or 1
    const int chunk = ((bx >> 3) << 2) + (xslot & 3);   // node chunk [0, n/4)
    const int wave  = threadIdx.x >> 6;
    const int lane  = threadIdx.x & 63;
    const int i     = chunk * 4 + wave;                 // node
    if (i >= n) return;

    const int qw = lane >> 4;        // quarter-wave 0..3 (edge slot)
    const int fl = lane & 15;        // feature group: 8 halves of this half
    const int fbase = half * 128 + fl * 8;

    const int start = rowptr[i];
    const int deg   = count[i];

    float accf[8] = {};
    if (qw == 0) {
        half8 l8 = *(const half8*)&lin_h[(size_t)i * 256 + fbase];
        #pragma unroll
        for (int t = 0; t < 8; ++t) accf[t] = (float)l8[t];
    } else if (qw == 1) {
        float di = dinv[i];
        float sn = di * di;
        half8 s8 = *(const half8*)&hw[(size_t)i * 256 + fbase];
        #pragma unroll
        for (int t = 0; t < 8; ++t) accf[t] = (float)s8[t] * sn;
    }

    for (int base = 0; base < deg; base += 64) {
        int m = deg - base;
        if (m > 64) m = 64;
        int2 meta = make_int2(0, 0);
        if (lane < m) meta = sorted_meta[start + base + lane];

        for (int j = 0; j < m; j += 16) {
            half8 hv[4];
            float nm[4];
            #pragma unroll
            for (int k2 = 0; k2 < 4; ++k2) {
                int e   = j + k2 * 4 + qw;
                int idx = (e < m) ? e : (m - 1);
                int s   = __shfl(meta.x, idx, 64);
                int nmb = __shfl(meta.y, idx, 64);
                nm[k2]  = (e < m) ? __int_as_float(nmb) : 0.0f;
                hv[k2]  = *(const half8*)&hw[(size_t)s * 256 + fbase];
            }
            #pragma unroll
            for (int k2 = 0; k2 < 4; ++k2)
                #pragma unroll
                for (int t = 0; t < 8; ++t)
                    accf[t] = fmaf((float)hv[k2][t], nm[k2], accf[t]);
        }
    }

    // combine quarter-wave partials (lanes fl, fl+16, fl+32, fl+48)
    #pragma unroll
    for (int t = 0; t < 8; ++t) {
        accf[t] += __shfl_xor(accf[t], 16, 64);
        accf[t] += __shfl_xor(accf[t], 32, 64);
    }

    if (qw == 0) {
        half8 o;
        #pragma unroll
        for (int t = 0; t < 8; ++t) o[t] = (_Float16)fmaxf(accf[t], 0.0f);
        *(half8*)&jk_col[(size_t)i * 1024 + fbase] = o;
    }
}

extern "C" void kernel_launch(void* const* d_in, const int* in_sizes, int n_in,
                              void* d_out, int out_size, void* d_ws, size_t ws_size,
                              hipStream_t stream) {
    const float* x        = (const float*)d_in[0];
    const int*   ei       = (const int*)d_in[1];
    const float* in_gc_W  = (const float*)d_in[2];
    const float* in_gc_b  = (const float*)d_in[3];
    const float* in_lin_W = (const float*)d_in[4];
    const float* in_lin_b = (const float*)d_in[5];
    const float* convs_W  = (const float*)d_in[6];
    const float* convs_b  = (const float*)d_in[7];
    const float* lins_W   = (const float*)d_in[8];
    const float* lins_b   = (const float*)d_in[9];
    const float* out_W    = (const float*)d_in[10];
    const float* out_b    = (const float*)d_in[11];

    const int N = 50000;
    const int E = in_sizes[1] / 2;
    const int F = 512, H = 256, L = 4, NC = 40;

    const int* src = ei;
    const int* dst = ei + E;

    char* ws = (char*)d_ws;
    auto carve = [&](size_t bytes) { void* p = ws; ws += (bytes + 255) & ~(size_t)255; return p; };
    float*    dinv        = (float*)carve((size_t)N * 4);
    int*      count       = (int*)  carve((size_t)N * 4);
    int*      incl        = (int*)  carve((size_t)N * 4);
    int*      rowptr      = (int*)  carve((size_t)N * 4);
    int*      cursor      = (int*)  carve((size_t)N * 4);
    int*      blocksum    = (int*)  carve(256 * 4);
    int*      blockoff    = (int*)  carve(256 * 4);
    int2*     sorted_meta = (int2*) carve((size_t)E * 8);
    _Float16* xh          = (_Float16*)carve((size_t)N * F * 2);
    _Float16* w0comb      = (_Float16*)carve((size_t)512 * F * 2);
    _Float16* wcomb       = (_Float16*)carve((size_t)3 * 512 * H * 2);
    _Float16* outWT       = (_Float16*)carve((size_t)NC * H * L * 2);
    _Float16* lin_h       = (_Float16*)carve((size_t)N * H * 2);
    _Float16* hw          = (_Float16*)carve((size_t)N * H * 2);
    _Float16* jk_h        = (_Float16*)carve((size_t)N * H * L * 2);
    float*    out         = (float*)d_out;

    const int nbN = (N + 255) / 256;
    const int nbE = (E + 255) / 256;

    // 1) CSR build + dinv
    zero_i32<<<nbN, 256, 0, stream>>>(count, N);
    hist_dst<<<nbE, 256, 0, stream>>>(dst, count, E);
    scan_block<<<nbN, 256, 0, stream>>>(count, incl, blocksum, dinv, N);
    scan_top<<<1, 256, 0, stream>>>(blocksum, blockoff, nbN);
    make_rowptr<<<nbN, 256, 0, stream>>>(incl, count, blockoff, rowptr, cursor, N);
    scatter_perm<<<nbE, 256, 0, stream>>>(src, dst, dinv, cursor, sorted_meta, E);

    // 2) casts / tiled transposes
    cast_f32_f16<<<(N * F / 4 + 255) / 256, 256, 0, stream>>>(x, xh, N * F / 4);
    {
        dim3 tg((F + 31) / 32, (H + 31) / 32);
        transpose_cast_tiled<<<tg, 256, 0, stream>>>(in_lin_W, w0comb,                F, H);
        transpose_cast_tiled<<<tg, 256, 0, stream>>>(in_gc_W,  w0comb + (size_t)H * F, F, H);
        dim3 th((H + 31) / 32, (H + 31) / 32);
        for (int l = 0; l < 3; ++l) {
            _Float16* wl = wcomb + (size_t)l * 512 * H;
            transpose_cast_tiled<<<th, 256, 0, stream>>>(lins_W  + (size_t)l * H * H, wl,                 H, H);
            transpose_cast_tiled<<<th, 256, 0, stream>>>(convs_W + (size_t)l * H * H, wl + (size_t)H * H, H, H);
        }
        dim3 to((H * L + 31) / 32, (NC + 31) / 32);
        transpose_cast_tiled<<<to, 256, 0, stream>>>(out_W, outWT, H * L, NC);
    }

    const dim3 dgrid(4, (N + 127) / 128);
    const dim3 ogrid(1, (N + 127) / 128);
    // aggregate: 4 nodes x 1 feature-half per block; chunks = N/4 = 12500 (x2 halves)
    const int agg_blocks = 2 * ((N + 3) / 4);   // 25000, divisible by 8

    // 3) layers
    for (int l = 0; l < L; ++l) {
        const _Float16* Ah = (l == 0) ? xh : (jk_h + (size_t)(l - 1) * H);
        int lda            = (l == 0) ? F : H * L;
        int K              = (l == 0) ? F : H;
        const _Float16* BT = (l == 0) ? w0comb : (wcomb + (size_t)(l - 1) * 512 * H);
        const float* gcB   = (l == 0) ? in_gc_b  : (convs_b + (size_t)(l - 1) * H);
        const float* liB   = (l == 0) ? in_lin_b : (lins_b  + (size_t)(l - 1) * H);

        gemm_mfma<true><<<dgrid, 256, 0, stream>>>(Ah, lda, BT, 512, liB, gcB,
                                                   lin_h, hw, nullptr, 0, N, K);
        aggregate_csr<<<agg_blocks, 256, 0, stream>>>(rowptr, count, sorted_meta,
                                                      dinv, hw, lin_h, jk_h + (size_t)l * H, N);
    }

    // 4) out = jk_h @ out_W + out_b
    gemm_mfma<false><<<ogrid, 256, 0, stream>>>(jk_h, H * L, outWT, NC, out_b, nullptr,
                                                nullptr, nullptr, out, NC, N, H * L);
}